// Round 1
// baseline (4850.254 us; speedup 1.0000x reference)
//
#include <hip/hip_runtime.h>
#include <hip/hip_bf16.h>
#include <math.h>

// Problem constants
#define BB 2
#define SS 2048
#define HH 2048
#define NH 16
#define QL 1536
#define KVL 512
#define DK 128
#define DR 64
#define DV 128
#define IHN 8
#define IDN 128
#define TOPK 8

// ---------------------------------------------------------------------------
// Generic fp32 GEMM: C[M,N] = A[M,K] @ B[K,N], row-major.
// Requirements: M % 128 == 0, K % 16 == 0, N % 4 == 0 (guarded on N).
// 256 threads, 128x128 tile, 8x8 per thread (rows 4ty+64i2+e, cols 4tx+64j2+e).
// ---------------------------------------------------------------------------
__global__ __launch_bounds__(256) void gemm128(const float* __restrict__ A,
                                               const float* __restrict__ Bm,
                                               float* __restrict__ C,
                                               int M, int N, int K) {
    __shared__ float Ast[16 * 132];  // A transposed: Ast[k][r], pitch 132
    __shared__ float Bs[16 * 132];   // Bs[k][c], pitch 132
    const int tid = threadIdx.x;
    const int tx = tid & 15, ty = tid >> 4;
    const int rowBase = blockIdx.y * 128;
    const int colBase = blockIdx.x * 128;

    float acc[8][8];
#pragma unroll
    for (int i = 0; i < 8; ++i)
#pragma unroll
        for (int j = 0; j < 8; ++j) acc[i][j] = 0.f;

    for (int k0 = 0; k0 < K; k0 += 16) {
        // stage A transposed: 128 rows x 16 k  (512 float4 / 256 threads)
#pragma unroll
        for (int it = 0; it < 2; ++it) {
            int s = tid + 256 * it;
            int r = s >> 2, kq = s & 3;
            float4 av = *(const float4*)(A + (size_t)(rowBase + r) * K + k0 + kq * 4);
            Ast[(kq * 4 + 0) * 132 + r] = av.x;
            Ast[(kq * 4 + 1) * 132 + r] = av.y;
            Ast[(kq * 4 + 2) * 132 + r] = av.z;
            Ast[(kq * 4 + 3) * 132 + r] = av.w;
        }
        // stage B: 16 k x 128 cols
#pragma unroll
        for (int it = 0; it < 2; ++it) {
            int s = tid + 256 * it;
            int kk = s >> 5, c4 = s & 31;
            int col = colBase + c4 * 4;
            float4 bv = make_float4(0.f, 0.f, 0.f, 0.f);
            if (col < N) bv = *(const float4*)(Bm + (size_t)(k0 + kk) * N + col);
            *(float4*)(Bs + kk * 132 + c4 * 4) = bv;
        }
        __syncthreads();
#pragma unroll 4
        for (int kk = 0; kk < 16; ++kk) {
            float4 a0 = *(const float4*)(Ast + kk * 132 + 4 * ty);
            float4 a1 = *(const float4*)(Ast + kk * 132 + 64 + 4 * ty);
            float4 b0 = *(const float4*)(Bs + kk * 132 + 4 * tx);
            float4 b1 = *(const float4*)(Bs + kk * 132 + 64 + 4 * tx);
            float av[8] = {a0.x, a0.y, a0.z, a0.w, a1.x, a1.y, a1.z, a1.w};
            float bv[8] = {b0.x, b0.y, b0.z, b0.w, b1.x, b1.y, b1.z, b1.w};
#pragma unroll
            for (int i = 0; i < 8; ++i)
#pragma unroll
                for (int j = 0; j < 8; ++j) acc[i][j] += av[i] * bv[j];
        }
        __syncthreads();
    }
    // write C (float4 per (row, j2))
#pragma unroll
    for (int i2 = 0; i2 < 2; ++i2)
#pragma unroll
        for (int e = 0; e < 4; ++e) {
            int row = rowBase + 4 * ty + 64 * i2 + e;
#pragma unroll
            for (int j2 = 0; j2 < 2; ++j2) {
                int col = colBase + 4 * tx + 64 * j2;
                if (col < N) {
                    float4 v = make_float4(acc[i2 * 4 + e][j2 * 4 + 0],
                                           acc[i2 * 4 + e][j2 * 4 + 1],
                                           acc[i2 * 4 + e][j2 * 4 + 2],
                                           acc[i2 * 4 + e][j2 * 4 + 3]);
                    *(float4*)(C + (size_t)row * N + col) = v;
                }
            }
        }
}

// ---------------------------------------------------------------------------
// RoPE cos/sin tables: [S][32]
// ---------------------------------------------------------------------------
__global__ void rope_tables_kernel(float* __restrict__ cosT, float* __restrict__ sinT) {
    int t = blockIdx.x * 256 + threadIdx.x;
    if (t >= SS * 32) return;
    int s = t >> 5, j = t & 31;
    // inv = 10000^(-j/32), computed in double, rounded to fp32 (matches numpy ~1 ulp)
    float inv = (float)exp(-log(10000.0) * (double)j / 32.0);
    float freq = (float)s * inv;  // fp32 multiply like np.outer
    cosT[t] = cosf(freq);
    sinT[t] = sinf(freq);
}

// ---------------------------------------------------------------------------
// RoPE in-place on x[rows][W]; pairs (h*64+2j, h*64+2j+1); lg = log2(W/2)
// ---------------------------------------------------------------------------
__global__ void rope_apply(float* __restrict__ x, const float* __restrict__ cosT,
                           const float* __restrict__ sinT, int W, int lg, int total) {
    int t = blockIdx.x * 256 + threadIdx.x;
    if (t >= total) return;
    int row = t >> lg;
    int rem = t & ((1 << lg) - 1);
    int j = rem & 31;
    int col = (rem >> 5) * 64 + 2 * j;
    int s = row & (SS - 1);
    float c = cosT[s * 32 + j], sn = sinT[s * 32 + j];
    float* p = x + (size_t)row * W + col;
    float xr = p[0], xi = p[1];
    p[0] = xr * c - xi * sn;
    p[1] = xr * sn + xi * c;
}

// ---------------------------------------------------------------------------
// top-k (k=8) of gate[:, :, ih] over S per (b, ih). Ties: lower index wins
// (matches jax.lax.top_k). One block of 256 threads per (b, ih).
// ---------------------------------------------------------------------------
__global__ void topk_kernel(const float* __restrict__ gate, int* __restrict__ topidx) {
    int bh = blockIdx.x;
    int b = bh >> 3, ih = bh & 7;
    __shared__ float svals[256];
    __shared__ int sidx[256];
    int tid = threadIdx.x;
    float v[8];
    int vi[8];
#pragma unroll
    for (int it = 0; it < 8; ++it) {
        int s = tid + 256 * it;
        v[it] = gate[(size_t)(b * SS + s) * IHN + ih];
        vi[it] = s;
    }
    for (int sel = 0; sel < 8; ++sel) {
        float best = -3.0e38f;
        int bidx = 1 << 30;
#pragma unroll
        for (int it = 0; it < 8; ++it) {
            if (v[it] > best || (v[it] == best && vi[it] < bidx)) { best = v[it]; bidx = vi[it]; }
        }
        svals[tid] = best;
        sidx[tid] = bidx;
        __syncthreads();
        for (int off = 128; off > 0; off >>= 1) {
            if (tid < off) {
                float ov = svals[tid + off];
                int oi = sidx[tid + off];
                if (ov > svals[tid] || (ov == svals[tid] && oi < sidx[tid])) {
                    svals[tid] = ov;
                    sidx[tid] = oi;
                }
            }
            __syncthreads();
        }
        int win = sidx[0];
        if (tid == 0) topidx[bh * 8 + sel] = win;
#pragma unroll
        for (int it = 0; it < 8; ++it)
            if (vi[it] == win) v[it] = -3.0e38f;
        __syncthreads();
    }
}

// ---------------------------------------------------------------------------
// Sparse indexer: per (b, ih) gather TOPK rows, 3 small 128x128 GEMMs,
// 8x8 softmax attention, mean over TOPK, project by W_iout[:, :128].
// io[b][ih][128]
// ---------------------------------------------------------------------------
__global__ void indexer_kernel(const float* __restrict__ idxs, const int* __restrict__ topidx,
                               const float* __restrict__ Wsq, const float* __restrict__ Wsk,
                               const float* __restrict__ Wsv, const float* __restrict__ Wiout,
                               float* __restrict__ io) {
    int bh = blockIdx.x;
    int b = bh >> 3, ih = bh & 7;
    __shared__ float sel[8][128], sq[8][128], sk[8][128], sv[8][128], sout[8][128];
    __shared__ float sprob[8][8];
    __shared__ float msout[128];
    __shared__ int tix[8];
    int tid = threadIdx.x;
    if (tid < 8) tix[tid] = topidx[bh * 8 + tid];
    __syncthreads();
#pragma unroll
    for (int it = 0; it < 4; ++it) {
        int s = tid + 256 * it;
        int t = s >> 7, d = s & 127;
        sel[t][d] = idxs[((size_t)(b * SS + tix[t])) * (IHN * IDN) + ih * IDN + d];
    }
    __syncthreads();
#pragma unroll
    for (int it = 0; it < 4; ++it) {
        int s = tid + 256 * it;
        int t = s >> 7, d = s & 127;
        float aq = 0.f, ak = 0.f, av = 0.f;
        for (int e = 0; e < 128; ++e) {
            float xv = sel[t][e];
            aq += xv * Wsq[e * 128 + d];
            ak += xv * Wsk[e * 128 + d];
            av += xv * Wsv[e * 128 + d];
        }
        sq[t][d] = aq;
        sk[t][d] = ak;
        sv[t][d] = av;
    }
    __syncthreads();
    if (tid < 64) {
        int t = tid >> 3, u = tid & 7;
        float a = 0.f;
        for (int d = 0; d < 128; ++d) a += sq[t][d] * sk[u][d];
        sprob[t][u] = a * 0.08838834764831845f;  // 1/sqrt(128)
    }
    __syncthreads();
    if (tid < 8) {
        int t = tid;
        float mx = -3.0e38f;
        for (int u = 0; u < 8; ++u) mx = fmaxf(mx, sprob[t][u]);
        float ssum = 0.f;
        for (int u = 0; u < 8; ++u) {
            float e = __expf(sprob[t][u] - mx);
            sprob[t][u] = e;
            ssum += e;
        }
        for (int u = 0; u < 8; ++u) sprob[t][u] /= ssum;
    }
    __syncthreads();
#pragma unroll
    for (int it = 0; it < 4; ++it) {
        int s = tid + 256 * it;
        int t = s >> 7, d = s & 127;
        float a = 0.f;
        for (int u = 0; u < 8; ++u) a += sprob[t][u] * sv[u][d];
        sout[t][d] = a;
    }
    __syncthreads();
    if (tid < 128) {
        float a = 0.f;
        for (int t = 0; t < 8; ++t) a += sout[t][tid];
        msout[tid] = a * 0.125f;
    }
    __syncthreads();
    if (tid < 128) {
        float a = 0.f;
        for (int d = 0; d < 128; ++d) a += msout[d] * Wiout[d * HH + tid];
        io[(b * IHN + ih) * 128 + tid] = a;
    }
}

// ---------------------------------------------------------------------------
// Flash attention (fp32 vector). Grid (32 qt reversed, NH, B), 256 threads.
// Q-tile 64, K-tile 64, d chunked 128 (k_c/q_c) + 64 (k_r/q_r).
// S-tile ownership: rows ty+16i, cols tx+16j. O: rows ty+16i, cols 4tx+64j2+e.
// LDS: ldsA = Q-chunk (pitch 132) or P (pitch 68); ldsB = K-chunk / V (pitch 132).
// Output written to attn[(b*S+q)*2048 + h*128 + d]  (== (B,S,NH*DV) layout).
// ---------------------------------------------------------------------------
__global__ __launch_bounds__(256) void mla_attn(const float* __restrict__ qc,
                                                const float* __restrict__ qr,
                                                const float* __restrict__ kc,
                                                const float* __restrict__ kr,
                                                const float* __restrict__ vb,
                                                float* __restrict__ attn) {
    __shared__ float ldsA[8448];
    __shared__ float ldsB[8448];
    const int qt = 31 - blockIdx.x;  // heavy blocks first
    const int h = blockIdx.y, b = blockIdx.z;
    const int tid = threadIdx.x;
    const int tx = tid & 15, ty = tid >> 4;
    const int qbase = qt * 64;
    const size_t rowQ = (size_t)(b * SS + qbase);
    const float scale = 0.072168783648703f;  // 1/sqrt(192)

    float m[4], l[4], o[4][8];
#pragma unroll
    for (int i = 0; i < 4; ++i) {
        m[i] = -1e30f;
        l[i] = 0.f;
#pragma unroll
        for (int j = 0; j < 8; ++j) o[i][j] = 0.f;
    }

    for (int kt = 0; kt <= qt; ++kt) {
        const int kbase = kt * 64;
        const size_t rowK = (size_t)(b * SS + kbase);
        float sacc[4][4];
#pragma unroll
        for (int i = 0; i < 4; ++i)
#pragma unroll
            for (int j = 0; j < 4; ++j) sacc[i][j] = 0.f;

        // ---- chunk 0: d = 0..127 from q_c / k_c ----
#pragma unroll
        for (int it = 0; it < 8; ++it) {
            int s = tid + 256 * it;
            int r = s >> 5, f4 = s & 31;
            *(float4*)(ldsA + r * 132 + f4 * 4) =
                *(const float4*)(qc + (rowQ + r) * (NH * DK) + h * DK + f4 * 4);
            *(float4*)(ldsB + r * 132 + f4 * 4) =
                *(const float4*)(kc + (rowK + r) * (NH * DK) + h * DK + f4 * 4);
        }
        __syncthreads();
        for (int d4 = 0; d4 < 32; ++d4) {
            float4 qa[4], kb[4];
#pragma unroll
            for (int i = 0; i < 4; ++i) qa[i] = *(const float4*)(ldsA + (ty + 16 * i) * 132 + d4 * 4);
#pragma unroll
            for (int j = 0; j < 4; ++j) kb[j] = *(const float4*)(ldsB + (tx + 16 * j) * 132 + d4 * 4);
#pragma unroll
            for (int i = 0; i < 4; ++i)
#pragma unroll
                for (int j = 0; j < 4; ++j)
                    sacc[i][j] += qa[i].x * kb[j].x + qa[i].y * kb[j].y +
                                  qa[i].z * kb[j].z + qa[i].w * kb[j].w;
        }
        __syncthreads();
        // ---- chunk 1: d = 128..191 from q_r / k_r (k_r head-independent) ----
#pragma unroll
        for (int it = 0; it < 4; ++it) {
            int s = tid + 256 * it;
            int r = s >> 4, f4 = s & 15;
            *(float4*)(ldsA + r * 132 + f4 * 4) =
                *(const float4*)(qr + (rowQ + r) * (NH * DR) + h * DR + f4 * 4);
            *(float4*)(ldsB + r * 132 + f4 * 4) =
                *(const float4*)(kr + (rowK + r) * DR + f4 * 4);
        }
        __syncthreads();
        for (int d4 = 0; d4 < 16; ++d4) {
            float4 qa[4], kb[4];
#pragma unroll
            for (int i = 0; i < 4; ++i) qa[i] = *(const float4*)(ldsA + (ty + 16 * i) * 132 + d4 * 4);
#pragma unroll
            for (int j = 0; j < 4; ++j) kb[j] = *(const float4*)(ldsB + (tx + 16 * j) * 132 + d4 * 4);
#pragma unroll
            for (int i = 0; i < 4; ++i)
#pragma unroll
                for (int j = 0; j < 4; ++j)
                    sacc[i][j] += qa[i].x * kb[j].x + qa[i].y * kb[j].y +
                                  qa[i].z * kb[j].z + qa[i].w * kb[j].w;
        }
        // ---- scale + causal mask + online softmax (registers + shfl) ----
#pragma unroll
        for (int i = 0; i < 4; ++i)
#pragma unroll
            for (int j = 0; j < 4; ++j) {
                float x = sacc[i][j] * scale;
                int kj = kbase + tx + 16 * j;
                int qi = qbase + ty + 16 * i;
                if (kj > qi) x = -1e30f;
                sacc[i][j] = x;
            }
#pragma unroll
        for (int i = 0; i < 4; ++i) {
            float mx = fmaxf(fmaxf(sacc[i][0], sacc[i][1]), fmaxf(sacc[i][2], sacc[i][3]));
            for (int msk = 1; msk < 16; msk <<= 1) mx = fmaxf(mx, __shfl_xor(mx, msk, 64));
            float mn = fmaxf(m[i], mx);
            float f = __expf(m[i] - mn);
            float rs = 0.f;
#pragma unroll
            for (int j = 0; j < 4; ++j) {
                float p = __expf(sacc[i][j] - mn);
                sacc[i][j] = p;
                rs += p;
            }
            for (int msk = 1; msk < 16; msk <<= 1) rs += __shfl_xor(rs, msk, 64);
            l[i] = l[i] * f + rs;
            m[i] = mn;
#pragma unroll
            for (int jj = 0; jj < 8; ++jj) o[i][jj] *= f;
        }
        __syncthreads();
        // ---- write P (pitch 68) and stage V ----
#pragma unroll
        for (int i = 0; i < 4; ++i)
#pragma unroll
            for (int j = 0; j < 4; ++j) ldsA[(ty + 16 * i) * 68 + tx + 16 * j] = sacc[i][j];
#pragma unroll
        for (int it = 0; it < 8; ++it) {
            int s = tid + 256 * it;
            int r = s >> 5, f4 = s & 31;
            *(float4*)(ldsB + r * 132 + f4 * 4) =
                *(const float4*)(vb + (rowK + r) * (NH * DV) + h * DV + f4 * 4);
        }
        __syncthreads();
        // ---- PV: O += P @ V ----
        for (int c = 0; c < 64; ++c) {
            float p[4];
#pragma unroll
            for (int i = 0; i < 4; ++i) p[i] = ldsA[(ty + 16 * i) * 68 + c];
            float4 v0 = *(const float4*)(ldsB + c * 132 + 4 * tx);
            float4 v1 = *(const float4*)(ldsB + c * 132 + 64 + 4 * tx);
#pragma unroll
            for (int i = 0; i < 4; ++i) {
                o[i][0] += p[i] * v0.x;
                o[i][1] += p[i] * v0.y;
                o[i][2] += p[i] * v0.z;
                o[i][3] += p[i] * v0.w;
                o[i][4] += p[i] * v1.x;
                o[i][5] += p[i] * v1.y;
                o[i][6] += p[i] * v1.z;
                o[i][7] += p[i] * v1.w;
            }
        }
        __syncthreads();
    }
    // ---- epilogue ----
#pragma unroll
    for (int i = 0; i < 4; ++i) {
        float inv = 1.f / l[i];
        size_t base = (rowQ + ty + 16 * i) * (NH * DV) + h * DV;
        float4 r0 = make_float4(o[i][0] * inv, o[i][1] * inv, o[i][2] * inv, o[i][3] * inv);
        float4 r1 = make_float4(o[i][4] * inv, o[i][5] * inv, o[i][6] * inv, o[i][7] * inv);
        *(float4*)(attn + base + 4 * tx) = r0;
        *(float4*)(attn + base + 64 + 4 * tx) = r1;
    }
}

// ---------------------------------------------------------------------------
// attn[b,s,h,d] += io[b, h/2, d]
// ---------------------------------------------------------------------------
__global__ void add_io(float* __restrict__ attn, const float* __restrict__ io) {
    int t = blockIdx.x * 256 + threadIdx.x;  // f4 index over 4096*2048
    int row = t >> 9, c4 = t & 511;
    int b = row >> 11;
    int col = c4 * 4;
    int hh = col >> 7, d = col & 127;
    float4 a = *(float4*)(attn + (size_t)row * (NH * DV) + col);
    const float4 iv = *(const float4*)(io + ((b << 3) + (hh >> 1)) * 128 + d);
    a.x += iv.x;
    a.y += iv.y;
    a.z += iv.z;
    a.w += iv.w;
    *(float4*)(attn + (size_t)row * (NH * DV) + col) = a;
}

// ---------------------------------------------------------------------------
// Launcher
// ---------------------------------------------------------------------------
extern "C" void kernel_launch(void* const* d_in, const int* in_sizes, int n_in,
                              void* d_out, int out_size, void* d_ws, size_t ws_size,
                              hipStream_t stream) {
    const float* x      = (const float*)d_in[0];
    const float* W_c    = (const float*)d_in[1];
    const float* W_cp   = (const float*)d_in[2];
    const float* W_qc   = (const float*)d_in[3];
    const float* W_qr   = (const float*)d_in[4];
    const float* W_kc   = (const float*)d_in[5];
    const float* W_kr   = (const float*)d_in[6];
    const float* W_v    = (const float*)d_in[7];
    const float* W_o    = (const float*)d_in[8];
    const float* W_idx  = (const float*)d_in[9];
    const float* W_gate = (const float*)d_in[10];
    const float* W_sq   = (const float*)d_in[11];
    const float* W_sk   = (const float*)d_in[12];
    const float* W_sv   = (const float*)d_in[13];
    const float* W_iout = (const float*)d_in[14];
    float* out = (float*)d_out;

    const int ROWS = BB * SS;  // 4096
    float* wsf = (float*)d_ws;
    size_t off = 0;
    auto alloc = [&](size_t n) {
        float* p = wsf + off;
        off += (n + 3) & ~(size_t)3;
        return p;
    };
    float* cosT = alloc(SS * 32);
    float* sinT = alloc(SS * 32);
    float* c    = alloc((size_t)ROWS * KVL);
    float* cp   = alloc((size_t)ROWS * QL);
    float* krb  = alloc((size_t)ROWS * DR);
    float* idxs = alloc((size_t)ROWS * IHN * IDN);
    float* gate = alloc((size_t)ROWS * IHN);
    float* qcb  = alloc((size_t)ROWS * NH * DK);
    float* qrb  = alloc((size_t)ROWS * NH * DR);
    float* kcb  = alloc((size_t)ROWS * NH * DK);
    float* vbuf = alloc((size_t)ROWS * NH * DV);
    float* attn = alloc((size_t)ROWS * NH * DV);
    float* io   = alloc(BB * IHN * 128);
    int* topidx = (int*)alloc(BB * IHN * TOPK);
    (void)ws_size; (void)n_in; (void)in_sizes; (void)out_size;

    rope_tables_kernel<<<(SS * 32 + 255) / 256, 256, 0, stream>>>(cosT, sinT);

    // projections from x
    gemm128<<<dim3(KVL / 128, ROWS / 128), 256, 0, stream>>>(x, W_c, c, ROWS, KVL, HH);
    gemm128<<<dim3(QL / 128, ROWS / 128), 256, 0, stream>>>(x, W_cp, cp, ROWS, QL, HH);
    gemm128<<<dim3(1, ROWS / 128), 256, 0, stream>>>(x, W_kr, krb, ROWS, DR, HH);
    gemm128<<<dim3(IHN * IDN / 128, ROWS / 128), 256, 0, stream>>>(x, W_idx, idxs, ROWS, IHN * IDN, HH);
    gemm128<<<dim3(1, ROWS / 128), 256, 0, stream>>>(x, W_gate, gate, ROWS, IHN, HH);

    // second-level projections
    gemm128<<<dim3(NH * DK / 128, ROWS / 128), 256, 0, stream>>>(cp, W_qc, qcb, ROWS, NH * DK, QL);
    gemm128<<<dim3(NH * DR / 128, ROWS / 128), 256, 0, stream>>>(cp, W_qr, qrb, ROWS, NH * DR, QL);
    gemm128<<<dim3(NH * DK / 128, ROWS / 128), 256, 0, stream>>>(c, W_kc, kcb, ROWS, NH * DK, KVL);
    gemm128<<<dim3(NH * DV / 128, ROWS / 128), 256, 0, stream>>>(c, W_v, vbuf, ROWS, NH * DV, KVL);

    // RoPE
    rope_apply<<<(ROWS * NH * 32 + 255) / 256, 256, 0, stream>>>(qrb, cosT, sinT, NH * DR, 9, ROWS * NH * 32);
    rope_apply<<<(ROWS * 32 + 255) / 256, 256, 0, stream>>>(krb, cosT, sinT, DR, 5, ROWS * 32);

    // sparse indexer path
    topk_kernel<<<BB * IHN, 256, 0, stream>>>(gate, topidx);
    indexer_kernel<<<BB * IHN, 256, 0, stream>>>(idxs, topidx, W_sq, W_sk, W_sv, W_iout, io);

    // attention
    mla_attn<<<dim3(SS / 64, NH, BB), 256, 0, stream>>>(qcb, qrb, kcb, krb, vbuf, attn);

    // attn += io broadcast
    add_io<<<(ROWS * NH * DV / 4) / 256, 256, 0, stream>>>(attn, io);

    // output projection
    gemm128<<<dim3(HH / 128, ROWS / 128), 256, 0, stream>>>(attn, W_o, out, ROWS, HH, HH);
}

// Round 7
// 1358.886 us; speedup vs baseline: 3.5693x; 3.5693x over previous
//
#include <hip/hip_runtime.h>
#include <hip/hip_bf16.h>
#include <math.h>

// Problem constants
#define BB 2
#define SS 2048
#define HH 2048
#define NH 16
#define QL 1536
#define KVL 512
#define DK 128
#define DR 64
#define DV 128
#define IHN 8
#define IDN 128
#define TOPK 8

typedef __attribute__((ext_vector_type(8))) short s16x8;
typedef __attribute__((ext_vector_type(4))) float f32x4;
typedef __attribute__((ext_vector_type(8))) unsigned short u16x8;

static __device__ __forceinline__ unsigned short f2b(float f) {
    unsigned int u = __float_as_uint(f);
    unsigned int r = (u + 0x7FFFu + ((u >> 16) & 1u)) >> 16;  // RNE
    return (unsigned short)r;
}

// ---------------------------------------------------------------------------
// Flat fp32 -> bf16 convert (4 elems/thread)
// ---------------------------------------------------------------------------
__global__ void cvt_bf16(const float* __restrict__ in, unsigned short* __restrict__ outp, int n4) {
    int t = blockIdx.x * 256 + threadIdx.x;
    if (t >= n4) return;
    float4 v = ((const float4*)in)[t];
    ushort4 o;
    o.x = f2b(v.x);
    o.y = f2b(v.y);
    o.z = f2b(v.z);
    o.w = f2b(v.w);
    ((ushort4*)outp)[t] = o;
}

// ---------------------------------------------------------------------------
// Transpose + convert: W[K][N] fp32 -> Wt[N][K] bf16. 32x32 tiles.
// ---------------------------------------------------------------------------
__global__ void cvtT_bf16(const float* __restrict__ W, unsigned short* __restrict__ Wt,
                          int K, int N) {
    __shared__ float tile[32][33];
    int k0 = blockIdx.x * 32, n0 = blockIdx.y * 32;
    int tx = threadIdx.x & 31, ty = threadIdx.x >> 5;
#pragma unroll
    for (int p = 0; p < 4; ++p) {
        int k = k0 + ty + 8 * p;
        if (k < K && n0 + tx < N) tile[ty + 8 * p][tx] = W[(size_t)k * N + n0 + tx];
    }
    __syncthreads();
#pragma unroll
    for (int p = 0; p < 4; ++p) {
        int n = n0 + ty + 8 * p;
        int k = k0 + tx;
        if (n < N && k < K) Wt[(size_t)n * K + k] = f2b(tile[tx][ty + 8 * p]);
    }
}

// ---------------------------------------------------------------------------
// MFMA bf16 GEMM: C[M,N] fp32 = A[M,K]bf16 @ Bt[N,K]bf16^T.
// 256 thr = 4 waves (2x2), tile 128x128, K-step 32, each wave 64x64 out.
// ---------------------------------------------------------------------------
__global__ __launch_bounds__(256) void gemm_bf16(const unsigned short* __restrict__ A,
                                                 const unsigned short* __restrict__ Bt,
                                                 float* __restrict__ C,
                                                 int M, int N, int K) {
    __shared__ unsigned short As[128][40];
    __shared__ unsigned short Bs[128][40];
    const int tid = threadIdx.x;
    const int lane = tid & 63, wv = tid >> 6;
    const int wr = wv >> 1, wc = wv & 1;
    const int l15 = lane & 15, g = lane >> 4;
    const int rowBase = blockIdx.y * 128, colBase = blockIdx.x * 128;

    f32x4 acc[4][4];
#pragma unroll
    for (int m = 0; m < 4; ++m)
#pragma unroll
        for (int n = 0; n < 4; ++n) acc[m][n] = (f32x4){0.f, 0.f, 0.f, 0.f};

    for (int k0 = 0; k0 < K; k0 += 32) {
#pragma unroll
        for (int it = 0; it < 2; ++it) {
            int s = tid + 256 * it;
            int r = s >> 2, blk = s & 3;
            u16x8 av = *(const u16x8*)(A + (size_t)(rowBase + r) * K + k0 + blk * 8);
            *(u16x8*)(&As[r][blk * 8]) = av;
            int brow = colBase + r;
            u16x8 bv = {};
            if (brow < N) bv = *(const u16x8*)(Bt + (size_t)brow * K + k0 + blk * 8);
            *(u16x8*)(&Bs[r][blk * 8]) = bv;
        }
        __syncthreads();
        s16x8 af[4], bfr[4];
#pragma unroll
        for (int m = 0; m < 4; ++m) af[m] = *(const s16x8*)(&As[wr * 64 + m * 16 + l15][g * 8]);
#pragma unroll
        for (int n = 0; n < 4; ++n) bfr[n] = *(const s16x8*)(&Bs[wc * 64 + n * 16 + l15][g * 8]);
#pragma unroll
        for (int m = 0; m < 4; ++m)
#pragma unroll
            for (int n = 0; n < 4; ++n)
                acc[m][n] = __builtin_amdgcn_mfma_f32_16x16x32_bf16(af[m], bfr[n], acc[m][n], 0, 0, 0);
        __syncthreads();
    }
#pragma unroll
    for (int m = 0; m < 4; ++m) {
        int row0 = rowBase + wr * 64 + m * 16 + g * 4;
#pragma unroll
        for (int n = 0; n < 4; ++n) {
            int col = colBase + wc * 64 + n * 16 + l15;
            if (col < N) {
#pragma unroll
                for (int r = 0; r < 4; ++r)
                    C[(size_t)(row0 + r) * N + col] = acc[m][n][r];
            }
        }
    }
}

// ---------------------------------------------------------------------------
// Generic fp32 GEMM (gate projection only: exact top-k inputs).
// ---------------------------------------------------------------------------
__global__ __launch_bounds__(256) void gemm128(const float* __restrict__ A,
                                               const float* __restrict__ Bm,
                                               float* __restrict__ C,
                                               int M, int N, int K) {
    __shared__ float Ast[16 * 132];
    __shared__ float Bs[16 * 132];
    const int tid = threadIdx.x;
    const int tx = tid & 15, ty = tid >> 4;
    const int rowBase = blockIdx.y * 128;
    const int colBase = blockIdx.x * 128;

    float acc[8][8];
#pragma unroll
    for (int i = 0; i < 8; ++i)
#pragma unroll
        for (int j = 0; j < 8; ++j) acc[i][j] = 0.f;

    for (int k0 = 0; k0 < K; k0 += 16) {
#pragma unroll
        for (int it = 0; it < 2; ++it) {
            int s = tid + 256 * it;
            int r = s >> 2, kq = s & 3;
            float4 av = *(const float4*)(A + (size_t)(rowBase + r) * K + k0 + kq * 4);
            Ast[(kq * 4 + 0) * 132 + r] = av.x;
            Ast[(kq * 4 + 1) * 132 + r] = av.y;
            Ast[(kq * 4 + 2) * 132 + r] = av.z;
            Ast[(kq * 4 + 3) * 132 + r] = av.w;
        }
#pragma unroll
        for (int it = 0; it < 2; ++it) {
            int s = tid + 256 * it;
            int kk = s >> 5, c4 = s & 31;
            int col = colBase + c4 * 4;
            float4 bv = make_float4(0.f, 0.f, 0.f, 0.f);
            if (col < N) bv = *(const float4*)(Bm + (size_t)(k0 + kk) * N + col);
            *(float4*)(Bs + kk * 132 + c4 * 4) = bv;
        }
        __syncthreads();
#pragma unroll 4
        for (int kk = 0; kk < 16; ++kk) {
            float4 a0 = *(const float4*)(Ast + kk * 132 + 4 * ty);
            float4 a1 = *(const float4*)(Ast + kk * 132 + 64 + 4 * ty);
            float4 b0 = *(const float4*)(Bs + kk * 132 + 4 * tx);
            float4 b1 = *(const float4*)(Bs + kk * 132 + 64 + 4 * tx);
            float av[8] = {a0.x, a0.y, a0.z, a0.w, a1.x, a1.y, a1.z, a1.w};
            float bv[8] = {b0.x, b0.y, b0.z, b0.w, b1.x, b1.y, b1.z, b1.w};
#pragma unroll
            for (int i = 0; i < 8; ++i)
#pragma unroll
                for (int j = 0; j < 8; ++j) acc[i][j] += av[i] * bv[j];
        }
        __syncthreads();
    }
#pragma unroll
    for (int i2 = 0; i2 < 2; ++i2)
#pragma unroll
        for (int e = 0; e < 4; ++e) {
            int row = rowBase + 4 * ty + 64 * i2 + e;
#pragma unroll
            for (int j2 = 0; j2 < 2; ++j2) {
                int col = colBase + 4 * tx + 64 * j2;
                if (col < N) {
                    float4 v = make_float4(acc[i2 * 4 + e][j2 * 4 + 0],
                                           acc[i2 * 4 + e][j2 * 4 + 1],
                                           acc[i2 * 4 + e][j2 * 4 + 2],
                                           acc[i2 * 4 + e][j2 * 4 + 3]);
                    *(float4*)(C + (size_t)row * N + col) = v;
                }
            }
        }
}

// ---------------------------------------------------------------------------
// RoPE cos/sin tables: [S][32]
// ---------------------------------------------------------------------------
__global__ void rope_tables_kernel(float* __restrict__ cosT, float* __restrict__ sinT) {
    int t = blockIdx.x * 256 + threadIdx.x;
    if (t >= SS * 32) return;
    int s = t >> 5, j = t & 31;
    float inv = (float)exp(-log(10000.0) * (double)j / 32.0);
    float freq = (float)s * inv;
    cosT[t] = cosf(freq);
    sinT[t] = sinf(freq);
}

// ---------------------------------------------------------------------------
// Fuse q_c + roped q_r -> qfull bf16 [row][h*192 + e]. One u16x8 per thread.
// ---------------------------------------------------------------------------
__global__ void fuse_rope_q(const float* __restrict__ qc, const float* __restrict__ qr,
                            const float* __restrict__ cosT, const float* __restrict__ sinT,
                            unsigned short* __restrict__ qfull) {
    int t = blockIdx.x * 256 + threadIdx.x;  // < 4096*16*24
    int ch = t % 24;
    int rh = t / 24;
    int h = rh & 15, row = rh >> 4;
    int s = row & (SS - 1);
    float v[8];
    if (ch < 16) {
        const float* p = qc + (size_t)row * (NH * DK) + h * DK + ch * 8;
#pragma unroll
        for (int i = 0; i < 8; ++i) v[i] = p[i];
    } else {
        int e0 = (ch - 16) * 8;
        const float* p = qr + (size_t)row * (NH * DR) + h * DR + e0;
        int jb = e0 >> 1;
#pragma unroll
        for (int q2 = 0; q2 < 4; ++q2) {
            float xr = p[2 * q2], xi = p[2 * q2 + 1];
            float cc = cosT[s * 32 + jb + q2], ss = sinT[s * 32 + jb + q2];
            v[2 * q2] = xr * cc - xi * ss;
            v[2 * q2 + 1] = xr * ss + xi * cc;
        }
    }
    u16x8 ov;
#pragma unroll
    for (int i = 0; i < 8; ++i) ov[i] = f2b(v[i]);
    *(u16x8*)(qfull + (size_t)rh * 192 + ch * 8) = ov;
}

// ---------------------------------------------------------------------------
// Fuse k_c + roped k_r (head-broadcast) -> kfull bf16 [row][h*192 + e].
// ---------------------------------------------------------------------------
__global__ void fuse_rope_k(const float* __restrict__ kc, const float* __restrict__ kr,
                            const float* __restrict__ cosT, const float* __restrict__ sinT,
                            unsigned short* __restrict__ kfull) {
    int t = blockIdx.x * 256 + threadIdx.x;
    int ch = t % 24;
    int rh = t / 24;
    int h = rh & 15, row = rh >> 4;
    int s = row & (SS - 1);
    float v[8];
    if (ch < 16) {
        const float* p = kc + (size_t)row * (NH * DK) + h * DK + ch * 8;
#pragma unroll
        for (int i = 0; i < 8; ++i) v[i] = p[i];
    } else {
        int e0 = (ch - 16) * 8;
        const float* p = kr + (size_t)row * DR + e0;  // head-independent
        int jb = e0 >> 1;
#pragma unroll
        for (int q2 = 0; q2 < 4; ++q2) {
            float xr = p[2 * q2], xi = p[2 * q2 + 1];
            float cc = cosT[s * 32 + jb + q2], ss = sinT[s * 32 + jb + q2];
            v[2 * q2] = xr * cc - xi * ss;
            v[2 * q2 + 1] = xr * ss + xi * cc;
        }
    }
    u16x8 ov;
#pragma unroll
    for (int i = 0; i < 8; ++i) ov[i] = f2b(v[i]);
    *(u16x8*)(kfull + (size_t)rh * 192 + ch * 8) = ov;
}

// ---------------------------------------------------------------------------
// Transpose V: vbuf fp32 [b*S+s][h*128+d] -> vtb bf16 [(b*16+h)*128+d][s]
// ---------------------------------------------------------------------------
__global__ void vtrans(const float* __restrict__ vb, unsigned short* __restrict__ vt) {
    __shared__ float tile[32][33];
    int s0 = blockIdx.x * 32, d0 = blockIdx.y * 32, bh = blockIdx.z;
    int b = bh >> 4, h = bh & 15;
    int tx = threadIdx.x & 31, ty = threadIdx.x >> 5;
#pragma unroll
    for (int p = 0; p < 4; ++p) {
        int s = s0 + ty + 8 * p;
        tile[ty + 8 * p][tx] = vb[(size_t)(b * SS + s) * (NH * DV) + h * DV + d0 + tx];
    }
    __syncthreads();
#pragma unroll
    for (int p = 0; p < 4; ++p) {
        int d = d0 + ty + 8 * p;
        vt[((size_t)bh * DV + d) * SS + s0 + tx] = f2b(tile[tx][ty + 8 * p]);
    }
}

// ---------------------------------------------------------------------------
// MFMA flash attention. Grid (32 qt reversed, NH, BB), 256 thr = 4 waves.
// Wave w owns Q-rows w*16..w*16+15. QK^T d=192 in 6 k-steps; softmax in regs
// (C layout row=g*4+r, col=l15); P->LDS bf16; PV vs pre-transposed V.
// LDS: Qs 25.6K persist | KVs 25.6K union (K then Vt) | Ps 9.2K = 60.4KB.
// ---------------------------------------------------------------------------
__global__ __launch_bounds__(256) void mla_attn_mfma(const unsigned short* __restrict__ qf,
                                                     const unsigned short* __restrict__ kf,
                                                     const unsigned short* __restrict__ vt,
                                                     float* __restrict__ attn) {
    __shared__ unsigned short Qs[64][200];
    __shared__ unsigned short KVs[12800];  // [64][200] K  OR  [128][72] Vt
    __shared__ unsigned short Ps[64][72];
    const int qt = 31 - blockIdx.x;
    const int h = blockIdx.y, b = blockIdx.z;
    const int tid = threadIdx.x;
    const int w = tid >> 6, lane = tid & 63;
    const int l15 = lane & 15, g = lane >> 4;
    const int qbase = qt * 64;
    const size_t rowQ = (size_t)b * SS + qbase;
    const int bh = b * NH + h;
    const float scale = 0.072168783648703f;  // 1/sqrt(192)

    // stage Q once: 64 rows x 24 chunks
#pragma unroll
    for (int it = 0; it < 6; ++it) {
        int idx = it * 256 + tid;
        int r = idx / 24, ch = idx % 24;
        *(u16x8*)(&Qs[r][ch * 8]) = *(const u16x8*)(qf + ((rowQ + r) * NH + h) * 192 + ch * 8);
    }

    float m[4], l[4];
    f32x4 accO[8];
#pragma unroll
    for (int r = 0; r < 4; ++r) {
        m[r] = -1e30f;
        l[r] = 0.f;
    }
#pragma unroll
    for (int nf = 0; nf < 8; ++nf) accO[nf] = (f32x4){0.f, 0.f, 0.f, 0.f};

    for (int kt = 0; kt <= qt; ++kt) {
        const int kbase = kt * 64;
        const size_t rowK = (size_t)b * SS + kbase;
        // stage K tile [64][200]
#pragma unroll
        for (int it = 0; it < 6; ++it) {
            int idx = it * 256 + tid;
            int r = idx / 24, ch = idx % 24;
            *(u16x8*)(&KVs[r * 200 + ch * 8]) =
                *(const u16x8*)(kf + ((rowK + r) * NH + h) * 192 + ch * 8);
        }
        __syncthreads();
        // QK^T over 6 k-steps
        f32x4 sa[4];
#pragma unroll
        for (int nf = 0; nf < 4; ++nf) sa[nf] = (f32x4){0.f, 0.f, 0.f, 0.f};
#pragma unroll
        for (int ks = 0; ks < 6; ++ks) {
            s16x8 a = *(const s16x8*)(&Qs[w * 16 + l15][ks * 32 + g * 8]);
#pragma unroll
            for (int nf = 0; nf < 4; ++nf) {
                s16x8 bb = *(const s16x8*)(&KVs[(nf * 16 + l15) * 200 + ks * 32 + g * 8]);
                sa[nf] = __builtin_amdgcn_mfma_f32_16x16x32_bf16(a, bb, sa[nf], 0, 0, 0);
            }
        }
        __syncthreads();  // QK^T reads done -> safe to overwrite KVs with Vt
        // stage Vt tile [128][72]
#pragma unroll
        for (int it = 0; it < 4; ++it) {
            int idx = it * 256 + tid;
            int d = idx >> 3, ch = idx & 7;
            *(u16x8*)(&KVs[d * 72 + ch * 8]) =
                *(const u16x8*)(vt + ((size_t)bh * DV + d) * SS + kbase + ch * 8);
        }
        // softmax (registers) + write P bf16
#pragma unroll
        for (int r = 0; r < 4; ++r) {
            int rowg = qbase + w * 16 + g * 4 + r;
            float x[4];
#pragma unroll
            for (int nf = 0; nf < 4; ++nf) {
                float xv = sa[nf][r] * scale;
                if (kbase + nf * 16 + l15 > rowg) xv = -1e30f;
                x[nf] = xv;
            }
            float mx = fmaxf(fmaxf(x[0], x[1]), fmaxf(x[2], x[3]));
            for (int msk = 1; msk < 16; msk <<= 1) mx = fmaxf(mx, __shfl_xor(mx, msk, 64));
            float mn = fmaxf(m[r], mx);
            float f = __expf(m[r] - mn);
            m[r] = mn;
            float p[4], rs = 0.f;
#pragma unroll
            for (int nf = 0; nf < 4; ++nf) {
                p[nf] = __expf(x[nf] - mn);
                rs += p[nf];
            }
            for (int msk = 1; msk < 16; msk <<= 1) rs += __shfl_xor(rs, msk, 64);
            l[r] = l[r] * f + rs;
#pragma unroll
            for (int nf = 0; nf < 8; ++nf) accO[nf][r] *= f;
            int prow = w * 16 + g * 4 + r;
#pragma unroll
            for (int nf = 0; nf < 4; ++nf) Ps[prow][nf * 16 + l15] = f2b(p[nf]);
        }
        __syncthreads();  // Vt staged AND Ps complete
        // PV: O += P @ V
#pragma unroll
        for (int ks = 0; ks < 2; ++ks) {
            s16x8 a = *(const s16x8*)(&Ps[w * 16 + l15][ks * 32 + g * 8]);
#pragma unroll
            for (int nf = 0; nf < 8; ++nf) {
                s16x8 bb = *(const s16x8*)(&KVs[(nf * 16 + l15) * 72 + ks * 32 + g * 8]);
                accO[nf] = __builtin_amdgcn_mfma_f32_16x16x32_bf16(a, bb, accO[nf], 0, 0, 0);
            }
        }
        __syncthreads();  // before next iteration overwrites KVs/Ps
    }
    // epilogue
#pragma unroll
    for (int r = 0; r < 4; ++r) {
        float inv = 1.f / l[r];
        size_t base = (rowQ + w * 16 + g * 4 + r) * (size_t)(NH * DV) + h * DV;
#pragma unroll
        for (int nf = 0; nf < 8; ++nf) attn[base + nf * 16 + l15] = accO[nf][r] * inv;
    }
}

// ---------------------------------------------------------------------------
// top-k (k=8), ties: lower index wins. One block per (b, ih).
// ---------------------------------------------------------------------------
__global__ void topk_kernel(const float* __restrict__ gate, int* __restrict__ topidx) {
    int bh = blockIdx.x;
    int b = bh >> 3, ih = bh & 7;
    __shared__ float svals[256];
    __shared__ int sidx[256];
    int tid = threadIdx.x;
    float v[8];
    int vi[8];
#pragma unroll
    for (int it = 0; it < 8; ++it) {
        int s = tid + 256 * it;
        v[it] = gate[(size_t)(b * SS + s) * IHN + ih];
        vi[it] = s;
    }
    for (int sel = 0; sel < 8; ++sel) {
        float best = -3.0e38f;
        int bidx = 1 << 30;
#pragma unroll
        for (int it = 0; it < 8; ++it) {
            if (v[it] > best || (v[it] == best && vi[it] < bidx)) { best = v[it]; bidx = vi[it]; }
        }
        svals[tid] = best;
        sidx[tid] = bidx;
        __syncthreads();
        for (int off = 128; off > 0; off >>= 1) {
            if (tid < off) {
                float ov = svals[tid + off];
                int oi = sidx[tid + off];
                if (ov > svals[tid] || (ov == svals[tid] && oi < sidx[tid])) {
                    svals[tid] = ov;
                    sidx[tid] = oi;
                }
            }
            __syncthreads();
        }
        int win = sidx[0];
        if (tid == 0) topidx[bh * 8 + sel] = win;
#pragma unroll
        for (int it = 0; it < 8; ++it)
            if (vi[it] == win) v[it] = -3.0e38f;
        __syncthreads();
    }
}

// ---------------------------------------------------------------------------
// Sparse indexer (fp32 exact): per (b, ih), io[b][ih][128]
// ---------------------------------------------------------------------------
__global__ void indexer_kernel(const float* __restrict__ idxs, const int* __restrict__ topidx,
                               const float* __restrict__ Wsq, const float* __restrict__ Wsk,
                               const float* __restrict__ Wsv, const float* __restrict__ Wiout,
                               float* __restrict__ io) {
    int bh = blockIdx.x;
    int b = bh >> 3, ih = bh & 7;
    __shared__ float sel[8][128], sq[8][128], sk[8][128], sv[8][128], sout[8][128];
    __shared__ float sprob[8][8];
    __shared__ float msout[128];
    __shared__ int tix[8];
    int tid = threadIdx.x;
    if (tid < 8) tix[tid] = topidx[bh * 8 + tid];
    __syncthreads();
#pragma unroll
    for (int it = 0; it < 4; ++it) {
        int s = tid + 256 * it;
        int t = s >> 7, d = s & 127;
        sel[t][d] = idxs[((size_t)(b * SS + tix[t])) * (IHN * IDN) + ih * IDN + d];
    }
    __syncthreads();
#pragma unroll
    for (int it = 0; it < 4; ++it) {
        int s = tid + 256 * it;
        int t = s >> 7, d = s & 127;
        float aq = 0.f, ak = 0.f, av = 0.f;
        for (int e = 0; e < 128; ++e) {
            float xv = sel[t][e];
            aq += xv * Wsq[e * 128 + d];
            ak += xv * Wsk[e * 128 + d];
            av += xv * Wsv[e * 128 + d];
        }
        sq[t][d] = aq;
        sk[t][d] = ak;
        sv[t][d] = av;
    }
    __syncthreads();
    if (tid < 64) {
        int t = tid >> 3, u = tid & 7;
        float a = 0.f;
        for (int d = 0; d < 128; ++d) a += sq[t][d] * sk[u][d];
        sprob[t][u] = a * 0.08838834764831845f;
    }
    __syncthreads();
    if (tid < 8) {
        int t = tid;
        float mx = -3.0e38f;
        for (int u = 0; u < 8; ++u) mx = fmaxf(mx, sprob[t][u]);
        float ssum = 0.f;
        for (int u = 0; u < 8; ++u) {
            float e = __expf(sprob[t][u] - mx);
            sprob[t][u] = e;
            ssum += e;
        }
        for (int u = 0; u < 8; ++u) sprob[t][u] /= ssum;
    }
    __syncthreads();
#pragma unroll
    for (int it = 0; it < 4; ++it) {
        int s = tid + 256 * it;
        int t = s >> 7, d = s & 127;
        float a = 0.f;
        for (int u = 0; u < 8; ++u) a += sprob[t][u] * sv[u][d];
        sout[t][d] = a;
    }
    __syncthreads();
    if (tid < 128) {
        float a = 0.f;
        for (int t = 0; t < 8; ++t) a += sout[t][tid];
        msout[tid] = a * 0.125f;
    }
    __syncthreads();
    if (tid < 128) {
        float a = 0.f;
        for (int d = 0; d < 128; ++d) a += msout[d] * Wiout[d * HH + tid];
        io[(b * IHN + ih) * 128 + tid] = a;
    }
}

// ---------------------------------------------------------------------------
// attn[b,s,h,d] += io[b, h/2, d]
// ---------------------------------------------------------------------------
__global__ void add_io(float* __restrict__ attn, const float* __restrict__ io) {
    int t = blockIdx.x * 256 + threadIdx.x;
    int row = t >> 9, c4 = t & 511;
    int b = row >> 11;
    int col = c4 * 4;
    int hh = col >> 7, d = col & 127;
    float4 a = *(float4*)(attn + (size_t)row * (NH * DV) + col);
    const float4 iv = *(const float4*)(io + ((b << 3) + (hh >> 1)) * 128 + d);
    a.x += iv.x;
    a.y += iv.y;
    a.z += iv.z;
    a.w += iv.w;
    *(float4*)(attn + (size_t)row * (NH * DV) + col) = a;
}

// ---------------------------------------------------------------------------
// Launcher
// ---------------------------------------------------------------------------
extern "C" void kernel_launch(void* const* d_in, const int* in_sizes, int n_in,
                              void* d_out, int out_size, void* d_ws, size_t ws_size,
                              hipStream_t stream) {
    const float* x      = (const float*)d_in[0];
    const float* W_c    = (const float*)d_in[1];
    const float* W_cp   = (const float*)d_in[2];
    const float* W_qc   = (const float*)d_in[3];
    const float* W_qr   = (const float*)d_in[4];
    const float* W_kc   = (const float*)d_in[5];
    const float* W_kr   = (const float*)d_in[6];
    const float* W_v    = (const float*)d_in[7];
    const float* W_o    = (const float*)d_in[8];
    const float* W_idx  = (const float*)d_in[9];
    const float* W_gate = (const float*)d_in[10];
    const float* W_sq   = (const float*)d_in[11];
    const float* W_sk   = (const float*)d_in[12];
    const float* W_sv   = (const float*)d_in[13];
    const float* W_iout = (const float*)d_in[14];
    float* out = (float*)d_out;

    const int ROWS = BB * SS;  // 4096
    float* wsf = (float*)d_ws;
    size_t off = 0;
    auto alloc = [&](size_t n) {
        float* p = wsf + off;
        off += (n + 3) & ~(size_t)3;
        return p;
    };
    auto allocU = [&](size_t n) { return (unsigned short*)alloc((n + 1) / 2); };
    // fp32 buffers
    float* cosT = alloc(SS * 32);
    float* sinT = alloc(SS * 32);
    float* c    = alloc((size_t)ROWS * KVL);
    float* cp   = alloc((size_t)ROWS * QL);       // -> kfull (bf16) after cvt->cpb
    float* krb  = alloc((size_t)ROWS * DR);
    float* idxs = alloc((size_t)ROWS * IHN * IDN);
    float* gate = alloc((size_t)ROWS * IHN);
    float* qcb  = alloc((size_t)ROWS * NH * DK);  // -> attn after fuse_rope_q
    float* qrb  = alloc((size_t)ROWS * NH * DR);
    float* kcb  = alloc((size_t)ROWS * NH * DK);  // -> attnb after fuse_rope_k
    float* vbuf = alloc((size_t)ROWS * NH * DV);  // -> qfull after vtrans
    float* io   = alloc(BB * IHN * 128);
    int* topidx = (int*)alloc(BB * IHN * TOPK);
    // bf16 buffers
    unsigned short* xb    = allocU((size_t)ROWS * HH);  // -> vtb after x-projections
    unsigned short* cb    = allocU((size_t)ROWS * KVL);
    unsigned short* cpb   = allocU((size_t)ROWS * QL);
    unsigned short* WcT   = allocU((size_t)HH * KVL);
    unsigned short* WcpT  = allocU((size_t)HH * QL);
    unsigned short* WqcT  = allocU((size_t)QL * NH * DK);
    unsigned short* WqrT  = allocU((size_t)QL * NH * DR);
    unsigned short* WkcT  = allocU((size_t)KVL * NH * DK);
    unsigned short* WkrT  = allocU((size_t)HH * DR);
    unsigned short* WvT   = allocU((size_t)KVL * NH * DV);
    unsigned short* WidxT = allocU((size_t)HH * IHN * IDN);
    unsigned short* WoT   = allocU((size_t)NH * DV * HH);
    // aliases (stream-ordered reuse; all size-checked: alias <= host buffer)
    unsigned short* kfull = (unsigned short*)cp;    // 24MB in 24MB
    unsigned short* vtb   = (unsigned short*)xb;    // 16MB in 16MB
    unsigned short* qfull = (unsigned short*)vbuf;  // 24MB in 32MB
    unsigned short* attnb = (unsigned short*)kcb;   // 16MB in 32MB
    float* attn           = qcb;                    // 32MB in 32MB
    (void)ws_size; (void)n_in; (void)in_sizes; (void)out_size;

    rope_tables_kernel<<<(SS * 32 + 255) / 256, 256, 0, stream>>>(cosT, sinT);

    // convert x and all GEMM weights (transpose) to bf16
    cvt_bf16<<<(ROWS * HH / 4 + 255) / 256, 256, 0, stream>>>(x, xb, ROWS * HH / 4);
    cvtT_bf16<<<dim3(HH / 32, KVL / 32), 256, 0, stream>>>(W_c, WcT, HH, KVL);
    cvtT_bf16<<<dim3(HH / 32, QL / 32), 256, 0, stream>>>(W_cp, WcpT, HH, QL);
    cvtT_bf16<<<dim3(QL / 32, NH * DK / 32), 256, 0, stream>>>(W_qc, WqcT, QL, NH * DK);
    cvtT_bf16<<<dim3(QL / 32, NH * DR / 32), 256, 0, stream>>>(W_qr, WqrT, QL, NH * DR);
    cvtT_bf16<<<dim3(KVL / 32, NH * DK / 32), 256, 0, stream>>>(W_kc, WkcT, KVL, NH * DK);
    cvtT_bf16<<<dim3(HH / 32, DR / 32), 256, 0, stream>>>(W_kr, WkrT, HH, DR);
    cvtT_bf16<<<dim3(KVL / 32, NH * DV / 32), 256, 0, stream>>>(W_v, WvT, KVL, NH * DV);
    cvtT_bf16<<<dim3(HH / 32, IHN * IDN / 32), 256, 0, stream>>>(W_idx, WidxT, HH, IHN * IDN);
    cvtT_bf16<<<dim3(NH * DV / 32, HH / 32), 256, 0, stream>>>(W_o, WoT, NH * DV, HH);

    // first-level projections (bf16 MFMA); gate exact fp32
    gemm_bf16<<<dim3(KVL / 128, ROWS / 128), 256, 0, stream>>>(xb, WcT, c, ROWS, KVL, HH);
    gemm_bf16<<<dim3(QL / 128, ROWS / 128), 256, 0, stream>>>(xb, WcpT, cp, ROWS, QL, HH);
    gemm_bf16<<<dim3(1, ROWS / 128), 256, 0, stream>>>(xb, WkrT, krb, ROWS, DR, HH);
    gemm_bf16<<<dim3(IHN * IDN / 128, ROWS / 128), 256, 0, stream>>>(xb, WidxT, idxs, ROWS, IHN * IDN, HH);
    gemm128<<<dim3(1, ROWS / 128), 256, 0, stream>>>(x, W_gate, gate, ROWS, IHN, HH);

    // second-level projections
    cvt_bf16<<<(ROWS * KVL / 4 + 255) / 256, 256, 0, stream>>>(c, cb, ROWS * KVL / 4);
    cvt_bf16<<<(ROWS * QL / 4 + 255) / 256, 256, 0, stream>>>(cp, cpb, ROWS * QL / 4);  // cp dead after
    gemm_bf16<<<dim3(NH * DK / 128, ROWS / 128), 256, 0, stream>>>(cpb, WqcT, qcb, ROWS, NH * DK, QL);
    gemm_bf16<<<dim3(NH * DR / 128, ROWS / 128), 256, 0, stream>>>(cpb, WqrT, qrb, ROWS, NH * DR, QL);
    gemm_bf16<<<dim3(NH * DK / 128, ROWS / 128), 256, 0, stream>>>(cb, WkcT, kcb, ROWS, NH * DK, KVL);
    gemm_bf16<<<dim3(NH * DV / 128, ROWS / 128), 256, 0, stream>>>(cb, WvT, vbuf, ROWS, NH * DV, KVL);

    // attention operand prep (order matters for aliases):
    // vtrans first (vbuf -> vtb), freeing vbuf for qfull
    vtrans<<<dim3(SS / 32, DV / 32, BB * NH), 256, 0, stream>>>(vbuf, vtb);
    const int fuseBlocks = ROWS * NH * 24 / 256;  // 6144
    fuse_rope_q<<<fuseBlocks, 256, 0, stream>>>(qcb, qrb, cosT, sinT, qfull);  // qcb dead after
    fuse_rope_k<<<fuseBlocks, 256, 0, stream>>>(kcb, krb, cosT, sinT, kfull);  // kcb dead after

    // sparse indexer path (fp32 exact)
    topk_kernel<<<BB * IHN, 256, 0, stream>>>(gate, topidx);
    indexer_kernel<<<BB * IHN, 256, 0, stream>>>(idxs, topidx, W_sq, W_sk, W_sv, W_iout, io);

    // attention (bf16 MFMA) -> attn (reuses qcb region)
    mla_attn_mfma<<<dim3(SS / 64, NH, BB), 256, 0, stream>>>(qfull, kfull, vtb, attn);

    // attn += io broadcast
    add_io<<<(ROWS * NH * DV / 4) / 256, 256, 0, stream>>>(attn, io);

    // output projection (bf16 MFMA)
    cvt_bf16<<<(ROWS * NH * DV / 4 + 255) / 256, 256, 0, stream>>>(attn, attnb, ROWS * NH * DV / 4);
    gemm_bf16<<<dim3(HH / 128, ROWS / 128), 256, 0, stream>>>(attnb, WoT, out, ROWS, HH, HH);
}

// Round 11
// 999.512 us; speedup vs baseline: 4.8526x; 1.3596x over previous
//
#include <hip/hip_runtime.h>
#include <hip/hip_bf16.h>
#include <math.h>

// Problem constants
#define BB 2
#define SS 2048
#define HH 2048
#define NH 16
#define QL 1536
#define KVL 512
#define DK 128
#define DR 64
#define DV 128
#define IHN 8
#define IDN 128
#define TOPK 8

typedef __attribute__((ext_vector_type(8))) short s16x8;
typedef __attribute__((ext_vector_type(4))) float f32x4;
typedef __attribute__((ext_vector_type(8))) unsigned short u16x8;

static __device__ __forceinline__ unsigned short f2b(float f) {
    unsigned int u = __float_as_uint(f);
    unsigned int r = (u + 0x7FFFu + ((u >> 16) & 1u)) >> 16;  // RNE
    return (unsigned short)r;
}

// ---------------------------------------------------------------------------
// Flat fp32 -> bf16 convert (4 elems/thread)
// ---------------------------------------------------------------------------
__global__ void cvt_bf16(const float* __restrict__ in, unsigned short* __restrict__ outp, int n4) {
    int t = blockIdx.x * 256 + threadIdx.x;
    if (t >= n4) return;
    float4 v = ((const float4*)in)[t];
    ushort4 o;
    o.x = f2b(v.x);
    o.y = f2b(v.y);
    o.z = f2b(v.z);
    o.w = f2b(v.w);
    ((ushort4*)outp)[t] = o;
}

// ---------------------------------------------------------------------------
// Transpose + convert: W[K][N] fp32 -> Wt[N][K] bf16. 32x32 tiles.
// ---------------------------------------------------------------------------
__global__ void cvtT_bf16(const float* __restrict__ W, unsigned short* __restrict__ Wt,
                          int K, int N) {
    __shared__ float tile[32][33];
    int k0 = blockIdx.x * 32, n0 = blockIdx.y * 32;
    int tx = threadIdx.x & 31, ty = threadIdx.x >> 5;
#pragma unroll
    for (int p = 0; p < 4; ++p) {
        int k = k0 + ty + 8 * p;
        if (k < K && n0 + tx < N) tile[ty + 8 * p][tx] = W[(size_t)k * N + n0 + tx];
    }
    __syncthreads();
#pragma unroll
    for (int p = 0; p < 4; ++p) {
        int n = n0 + ty + 8 * p;
        int k = k0 + tx;
        if (n < N && k < K) Wt[(size_t)n * K + k] = f2b(tile[tx][ty + 8 * p]);
    }
}

// ---------------------------------------------------------------------------
// MFMA bf16 GEMM: C[M,N] fp32 = A[M,K]bf16 @ Bt[N,K]bf16^T.
// 256 thr = 4 waves (2x2), tile 128x128, K-step 32, each wave 64x64 out.
// ---------------------------------------------------------------------------
__global__ __launch_bounds__(256) void gemm_bf16(const unsigned short* __restrict__ A,
                                                 const unsigned short* __restrict__ Bt,
                                                 float* __restrict__ C,
                                                 int M, int N, int K) {
    __shared__ unsigned short As[128][40];
    __shared__ unsigned short Bs[128][40];
    const int tid = threadIdx.x;
    const int lane = tid & 63, wv = tid >> 6;
    const int wr = wv >> 1, wc = wv & 1;
    const int l15 = lane & 15, g = lane >> 4;
    const int rowBase = blockIdx.y * 128, colBase = blockIdx.x * 128;

    f32x4 acc[4][4];
#pragma unroll
    for (int m = 0; m < 4; ++m)
#pragma unroll
        for (int n = 0; n < 4; ++n) acc[m][n] = (f32x4){0.f, 0.f, 0.f, 0.f};

    for (int k0 = 0; k0 < K; k0 += 32) {
#pragma unroll
        for (int it = 0; it < 2; ++it) {
            int s = tid + 256 * it;
            int r = s >> 2, blk = s & 3;
            u16x8 av = *(const u16x8*)(A + (size_t)(rowBase + r) * K + k0 + blk * 8);
            *(u16x8*)(&As[r][blk * 8]) = av;
            int brow = colBase + r;
            u16x8 bv = {};
            if (brow < N) bv = *(const u16x8*)(Bt + (size_t)brow * K + k0 + blk * 8);
            *(u16x8*)(&Bs[r][blk * 8]) = bv;
        }
        __syncthreads();
        s16x8 af[4], bfr[4];
#pragma unroll
        for (int m = 0; m < 4; ++m) af[m] = *(const s16x8*)(&As[wr * 64 + m * 16 + l15][g * 8]);
#pragma unroll
        for (int n = 0; n < 4; ++n) bfr[n] = *(const s16x8*)(&Bs[wc * 64 + n * 16 + l15][g * 8]);
#pragma unroll
        for (int m = 0; m < 4; ++m)
#pragma unroll
            for (int n = 0; n < 4; ++n)
                acc[m][n] = __builtin_amdgcn_mfma_f32_16x16x32_bf16(af[m], bfr[n], acc[m][n], 0, 0, 0);
        __syncthreads();
    }
#pragma unroll
    for (int m = 0; m < 4; ++m) {
        int row0 = rowBase + wr * 64 + m * 16 + g * 4;
#pragma unroll
        for (int n = 0; n < 4; ++n) {
            int col = colBase + wc * 64 + n * 16 + l15;
            if (col < N) {
#pragma unroll
                for (int r = 0; r < 4; ++r)
                    C[(size_t)(row0 + r) * N + col] = acc[m][n][r];
            }
        }
    }
}

// ---------------------------------------------------------------------------
// Skinny fp32 gate GEMM: gate[4096][8] = x[4096][2048] @ W_gate[2048][8].
// One block per row; 256 threads; each thread handles 8 k's x 8 cols;
// 64-lane shfl reduce + cross-wave LDS reduce. Exact fp32 for top-k.
// ---------------------------------------------------------------------------
__global__ __launch_bounds__(256) void gate_gemm(const float* __restrict__ x,
                                                 const float* __restrict__ Wg,
                                                 float* __restrict__ gate) {
    const int row = blockIdx.x;
    const int tid = threadIdx.x;
    const int wv = tid >> 6, lane = tid & 63;
    const float* xr = x + (size_t)row * HH;
    float acc[8];
#pragma unroll
    for (int i = 0; i < 8; ++i) acc[i] = 0.f;
#pragma unroll
    for (int it = 0; it < HH / 256; ++it) {
        int k = it * 256 + tid;
        float xv = xr[k];
        float4 w0 = *(const float4*)(Wg + (size_t)k * IHN);
        float4 w1 = *(const float4*)(Wg + (size_t)k * IHN + 4);
        acc[0] += xv * w0.x;
        acc[1] += xv * w0.y;
        acc[2] += xv * w0.z;
        acc[3] += xv * w0.w;
        acc[4] += xv * w1.x;
        acc[5] += xv * w1.y;
        acc[6] += xv * w1.z;
        acc[7] += xv * w1.w;
    }
#pragma unroll
    for (int i = 0; i < 8; ++i)
        for (int msk = 1; msk < 64; msk <<= 1) acc[i] += __shfl_xor(acc[i], msk, 64);
    __shared__ float part[4][8];
    if (lane == 0) {
#pragma unroll
        for (int i = 0; i < 8; ++i) part[wv][i] = acc[i];
    }
    __syncthreads();
    if (tid < 8) {
        gate[(size_t)row * IHN + tid] =
            part[0][tid] + part[1][tid] + part[2][tid] + part[3][tid];
    }
}

// ---------------------------------------------------------------------------
// RoPE cos/sin tables: [S][32]
// ---------------------------------------------------------------------------
__global__ void rope_tables_kernel(float* __restrict__ cosT, float* __restrict__ sinT) {
    int t = blockIdx.x * 256 + threadIdx.x;
    if (t >= SS * 32) return;
    int s = t >> 5, j = t & 31;
    float inv = (float)exp(-log(10000.0) * (double)j / 32.0);
    float freq = (float)s * inv;
    cosT[t] = cosf(freq);
    sinT[t] = sinf(freq);
}

// ---------------------------------------------------------------------------
// Fuse q_c + roped q_r -> qfull bf16 [row][h*192 + e]. One u16x8 per thread.
// ---------------------------------------------------------------------------
__global__ void fuse_rope_q(const float* __restrict__ qc, const float* __restrict__ qr,
                            const float* __restrict__ cosT, const float* __restrict__ sinT,
                            unsigned short* __restrict__ qfull) {
    int t = blockIdx.x * 256 + threadIdx.x;  // < 4096*16*24
    int ch = t % 24;
    int rh = t / 24;
    int h = rh & 15, row = rh >> 4;
    int s = row & (SS - 1);
    float v[8];
    if (ch < 16) {
        const float* p = qc + (size_t)row * (NH * DK) + h * DK + ch * 8;
#pragma unroll
        for (int i = 0; i < 8; ++i) v[i] = p[i];
    } else {
        int e0 = (ch - 16) * 8;
        const float* p = qr + (size_t)row * (NH * DR) + h * DR + e0;
        int jb = e0 >> 1;
#pragma unroll
        for (int q2 = 0; q2 < 4; ++q2) {
            float xr = p[2 * q2], xi = p[2 * q2 + 1];
            float cc = cosT[s * 32 + jb + q2], ss = sinT[s * 32 + jb + q2];
            v[2 * q2] = xr * cc - xi * ss;
            v[2 * q2 + 1] = xr * ss + xi * cc;
        }
    }
    u16x8 ov;
#pragma unroll
    for (int i = 0; i < 8; ++i) ov[i] = f2b(v[i]);
    *(u16x8*)(qfull + (size_t)rh * 192 + ch * 8) = ov;
}

// ---------------------------------------------------------------------------
// Fuse k_c + roped k_r (head-broadcast) -> kfull bf16 [row][h*192 + e].
// ---------------------------------------------------------------------------
__global__ void fuse_rope_k(const float* __restrict__ kc, const float* __restrict__ kr,
                            const float* __restrict__ cosT, const float* __restrict__ sinT,
                            unsigned short* __restrict__ kfull) {
    int t = blockIdx.x * 256 + threadIdx.x;
    int ch = t % 24;
    int rh = t / 24;
    int h = rh & 15, row = rh >> 4;
    int s = row & (SS - 1);
    float v[8];
    if (ch < 16) {
        const float* p = kc + (size_t)row * (NH * DK) + h * DK + ch * 8;
#pragma unroll
        for (int i = 0; i < 8; ++i) v[i] = p[i];
    } else {
        int e0 = (ch - 16) * 8;
        const float* p = kr + (size_t)row * DR + e0;  // head-independent
        int jb = e0 >> 1;
#pragma unroll
        for (int q2 = 0; q2 < 4; ++q2) {
            float xr = p[2 * q2], xi = p[2 * q2 + 1];
            float cc = cosT[s * 32 + jb + q2], ss = sinT[s * 32 + jb + q2];
            v[2 * q2] = xr * cc - xi * ss;
            v[2 * q2 + 1] = xr * ss + xi * cc;
        }
    }
    u16x8 ov;
#pragma unroll
    for (int i = 0; i < 8; ++i) ov[i] = f2b(v[i]);
    *(u16x8*)(kfull + (size_t)rh * 192 + ch * 8) = ov;
}

// ---------------------------------------------------------------------------
// Transpose V: vbuf fp32 [b*S+s][h*128+d] -> vtb bf16 [(b*16+h)*128+d][s]
// ---------------------------------------------------------------------------
__global__ void vtrans(const float* __restrict__ vb, unsigned short* __restrict__ vt) {
    __shared__ float tile[32][33];
    int s0 = blockIdx.x * 32, d0 = blockIdx.y * 32, bh = blockIdx.z;
    int b = bh >> 4, h = bh & 15;
    int tx = threadIdx.x & 31, ty = threadIdx.x >> 5;
#pragma unroll
    for (int p = 0; p < 4; ++p) {
        int s = s0 + ty + 8 * p;
        tile[ty + 8 * p][tx] = vb[(size_t)(b * SS + s) * (NH * DV) + h * DV + d0 + tx];
    }
    __syncthreads();
#pragma unroll
    for (int p = 0; p < 4; ++p) {
        int d = d0 + ty + 8 * p;
        vt[((size_t)bh * DV + d) * SS + s0 + tx] = f2b(tile[tx][ty + 8 * p]);
    }
}

// ---------------------------------------------------------------------------
// MFMA flash attention. Grid (32 qt reversed, NH, BB), 256 thr = 4 waves.
// Wave w owns Q-rows w*16..w*16+15. QK^T d=192 in 6 k-steps; softmax in regs
// (C layout row=g*4+r, col=l15); P->LDS bf16; PV vs pre-transposed V.
// LDS: Qs 25.6K persist | KVs 25.6K union (K then Vt) | Ps 9.2K = 60.4KB.
// ---------------------------------------------------------------------------
__global__ __launch_bounds__(256) void mla_attn_mfma(const unsigned short* __restrict__ qf,
                                                     const unsigned short* __restrict__ kf,
                                                     const unsigned short* __restrict__ vt,
                                                     float* __restrict__ attn) {
    __shared__ unsigned short Qs[64][200];
    __shared__ unsigned short KVs[12800];  // [64][200] K  OR  [128][72] Vt
    __shared__ unsigned short Ps[64][72];
    const int qt = 31 - blockIdx.x;
    const int h = blockIdx.y, b = blockIdx.z;
    const int tid = threadIdx.x;
    const int w = tid >> 6, lane = tid & 63;
    const int l15 = lane & 15, g = lane >> 4;
    const int qbase = qt * 64;
    const size_t rowQ = (size_t)b * SS + qbase;
    const int bh = b * NH + h;
    const float scale = 0.072168783648703f;  // 1/sqrt(192)

    // stage Q once: 64 rows x 24 chunks
#pragma unroll
    for (int it = 0; it < 6; ++it) {
        int idx = it * 256 + tid;
        int r = idx / 24, ch = idx % 24;
        *(u16x8*)(&Qs[r][ch * 8]) = *(const u16x8*)(qf + ((rowQ + r) * NH + h) * 192 + ch * 8);
    }

    float m[4], l[4];
    f32x4 accO[8];
#pragma unroll
    for (int r = 0; r < 4; ++r) {
        m[r] = -1e30f;
        l[r] = 0.f;
    }
#pragma unroll
    for (int nf = 0; nf < 8; ++nf) accO[nf] = (f32x4){0.f, 0.f, 0.f, 0.f};

    for (int kt = 0; kt <= qt; ++kt) {
        const int kbase = kt * 64;
        const size_t rowK = (size_t)b * SS + kbase;
        // stage K tile [64][200]
#pragma unroll
        for (int it = 0; it < 6; ++it) {
            int idx = it * 256 + tid;
            int r = idx / 24, ch = idx % 24;
            *(u16x8*)(&KVs[r * 200 + ch * 8]) =
                *(const u16x8*)(kf + ((rowK + r) * NH + h) * 192 + ch * 8);
        }
        __syncthreads();
        // QK^T over 6 k-steps
        f32x4 sa[4];
#pragma unroll
        for (int nf = 0; nf < 4; ++nf) sa[nf] = (f32x4){0.f, 0.f, 0.f, 0.f};
#pragma unroll
        for (int ks = 0; ks < 6; ++ks) {
            s16x8 a = *(const s16x8*)(&Qs[w * 16 + l15][ks * 32 + g * 8]);
#pragma unroll
            for (int nf = 0; nf < 4; ++nf) {
                s16x8 bb = *(const s16x8*)(&KVs[(nf * 16 + l15) * 200 + ks * 32 + g * 8]);
                sa[nf] = __builtin_amdgcn_mfma_f32_16x16x32_bf16(a, bb, sa[nf], 0, 0, 0);
            }
        }
        __syncthreads();  // QK^T reads done -> safe to overwrite KVs with Vt
        // stage Vt tile [128][72]
#pragma unroll
        for (int it = 0; it < 4; ++it) {
            int idx = it * 256 + tid;
            int d = idx >> 3, ch = idx & 7;
            *(u16x8*)(&KVs[d * 72 + ch * 8]) =
                *(const u16x8*)(vt + ((size_t)bh * DV + d) * SS + kbase + ch * 8);
        }
        // softmax (registers) + write P bf16
#pragma unroll
        for (int r = 0; r < 4; ++r) {
            int rowg = qbase + w * 16 + g * 4 + r;
            float x[4];
#pragma unroll
            for (int nf = 0; nf < 4; ++nf) {
                float xv = sa[nf][r] * scale;
                if (kbase + nf * 16 + l15 > rowg) xv = -1e30f;
                x[nf] = xv;
            }
            float mx = fmaxf(fmaxf(x[0], x[1]), fmaxf(x[2], x[3]));
            for (int msk = 1; msk < 16; msk <<= 1) mx = fmaxf(mx, __shfl_xor(mx, msk, 64));
            float mn = fmaxf(m[r], mx);
            float f = __expf(m[r] - mn);
            m[r] = mn;
            float p[4], rs = 0.f;
#pragma unroll
            for (int nf = 0; nf < 4; ++nf) {
                p[nf] = __expf(x[nf] - mn);
                rs += p[nf];
            }
            for (int msk = 1; msk < 16; msk <<= 1) rs += __shfl_xor(rs, msk, 64);
            l[r] = l[r] * f + rs;
#pragma unroll
            for (int nf = 0; nf < 8; ++nf) accO[nf][r] *= f;
            int prow = w * 16 + g * 4 + r;
#pragma unroll
            for (int nf = 0; nf < 4; ++nf) Ps[prow][nf * 16 + l15] = f2b(p[nf]);
        }
        __syncthreads();  // Vt staged AND Ps complete
        // PV: O += P @ V
#pragma unroll
        for (int ks = 0; ks < 2; ++ks) {
            s16x8 a = *(const s16x8*)(&Ps[w * 16 + l15][ks * 32 + g * 8]);
#pragma unroll
            for (int nf = 0; nf < 8; ++nf) {
                s16x8 bb = *(const s16x8*)(&KVs[(nf * 16 + l15) * 72 + ks * 32 + g * 8]);
                accO[nf] = __builtin_amdgcn_mfma_f32_16x16x32_bf16(a, bb, accO[nf], 0, 0, 0);
            }
        }
        __syncthreads();  // before next iteration overwrites KVs/Ps
    }
    // epilogue
#pragma unroll
    for (int r = 0; r < 4; ++r) {
        float inv = 1.f / l[r];
        size_t base = (rowQ + w * 16 + g * 4 + r) * (size_t)(NH * DV) + h * DV;
#pragma unroll
        for (int nf = 0; nf < 8; ++nf) attn[base + nf * 16 + l15] = accO[nf][r] * inv;
    }
}

// ---------------------------------------------------------------------------
// top-k (k=8), ties: lower index wins. One block per (b, ih).
// ---------------------------------------------------------------------------
__global__ void topk_kernel(const float* __restrict__ gate, int* __restrict__ topidx) {
    int bh = blockIdx.x;
    int b = bh >> 3, ih = bh & 7;
    __shared__ float svals[256];
    __shared__ int sidx[256];
    int tid = threadIdx.x;
    float v[8];
    int vi[8];
#pragma unroll
    for (int it = 0; it < 8; ++it) {
        int s = tid + 256 * it;
        v[it] = gate[(size_t)(b * SS + s) * IHN + ih];
        vi[it] = s;
    }
    for (int sel = 0; sel < 8; ++sel) {
        float best = -3.0e38f;
        int bidx = 1 << 30;
#pragma unroll
        for (int it = 0; it < 8; ++it) {
            if (v[it] > best || (v[it] == best && vi[it] < bidx)) { best = v[it]; bidx = vi[it]; }
        }
        svals[tid] = best;
        sidx[tid] = bidx;
        __syncthreads();
        for (int off = 128; off > 0; off >>= 1) {
            if (tid < off) {
                float ov = svals[tid + off];
                int oi = sidx[tid + off];
                if (ov > svals[tid] || (ov == svals[tid] && oi < sidx[tid])) {
                    svals[tid] = ov;
                    sidx[tid] = oi;
                }
            }
            __syncthreads();
        }
        int win = sidx[0];
        if (tid == 0) topidx[bh * 8 + sel] = win;
#pragma unroll
        for (int it = 0; it < 8; ++it)
            if (vi[it] == win) v[it] = -3.0e38f;
        __syncthreads();
    }
}

// ---------------------------------------------------------------------------
// Sparse indexer (fp32 exact): per (b, ih), io[b][ih][128]
// ---------------------------------------------------------------------------
__global__ void indexer_kernel(const float* __restrict__ idxs, const int* __restrict__ topidx,
                               const float* __restrict__ Wsq, const float* __restrict__ Wsk,
                               const float* __restrict__ Wsv, const float* __restrict__ Wiout,
                               float* __restrict__ io) {
    int bh = blockIdx.x;
    int b = bh >> 3, ih = bh & 7;
    __shared__ float sel[8][128], sq[8][128], sk[8][128], sv[8][128], sout[8][128];
    __shared__ float sprob[8][8];
    __shared__ float msout[128];
    __shared__ int tix[8];
    int tid = threadIdx.x;
    if (tid < 8) tix[tid] = topidx[bh * 8 + tid];
    __syncthreads();
#pragma unroll
    for (int it = 0; it < 4; ++it) {
        int s = tid + 256 * it;
        int t = s >> 7, d = s & 127;
        sel[t][d] = idxs[((size_t)(b * SS + tix[t])) * (IHN * IDN) + ih * IDN + d];
    }
    __syncthreads();
#pragma unroll
    for (int it = 0; it < 4; ++it) {
        int s = tid + 256 * it;
        int t = s >> 7, d = s & 127;
        float aq = 0.f, ak = 0.f, av = 0.f;
        for (int e = 0; e < 128; ++e) {
            float xv = sel[t][e];
            aq += xv * Wsq[e * 128 + d];
            ak += xv * Wsk[e * 128 + d];
            av += xv * Wsv[e * 128 + d];
        }
        sq[t][d] = aq;
        sk[t][d] = ak;
        sv[t][d] = av;
    }
    __syncthreads();
    if (tid < 64) {
        int t = tid >> 3, u = tid & 7;
        float a = 0.f;
        for (int d = 0; d < 128; ++d) a += sq[t][d] * sk[u][d];
        sprob[t][u] = a * 0.08838834764831845f;
    }
    __syncthreads();
    if (tid < 8) {
        int t = tid;
        float mx = -3.0e38f;
        for (int u = 0; u < 8; ++u) mx = fmaxf(mx, sprob[t][u]);
        float ssum = 0.f;
        for (int u = 0; u < 8; ++u) {
            float e = __expf(sprob[t][u] - mx);
            sprob[t][u] = e;
            ssum += e;
        }
        for (int u = 0; u < 8; ++u) sprob[t][u] /= ssum;
    }
    __syncthreads();
#pragma unroll
    for (int it = 0; it < 4; ++it) {
        int s = tid + 256 * it;
        int t = s >> 7, d = s & 127;
        float a = 0.f;
        for (int u = 0; u < 8; ++u) a += sprob[t][u] * sv[u][d];
        sout[t][d] = a;
    }
    __syncthreads();
    if (tid < 128) {
        float a = 0.f;
        for (int t = 0; t < 8; ++t) a += sout[t][tid];
        msout[tid] = a * 0.125f;
    }
    __syncthreads();
    if (tid < 128) {
        float a = 0.f;
        for (int d = 0; d < 128; ++d) a += msout[d] * Wiout[d * HH + tid];
        io[(b * IHN + ih) * 128 + tid] = a;
    }
}

// ---------------------------------------------------------------------------
// attn[b,s,h,d] += io[b, h/2, d]
// ---------------------------------------------------------------------------
__global__ void add_io(float* __restrict__ attn, const float* __restrict__ io) {
    int t = blockIdx.x * 256 + threadIdx.x;
    int row = t >> 9, c4 = t & 511;
    int b = row >> 11;
    int col = c4 * 4;
    int hh = col >> 7, d = col & 127;
    float4 a = *(float4*)(attn + (size_t)row * (NH * DV) + col);
    const float4 iv = *(const float4*)(io + ((b << 3) + (hh >> 1)) * 128 + d);
    a.x += iv.x;
    a.y += iv.y;
    a.z += iv.z;
    a.w += iv.w;
    *(float4*)(attn + (size_t)row * (NH * DV) + col) = a;
}

// ---------------------------------------------------------------------------
// Launcher
// ---------------------------------------------------------------------------
extern "C" void kernel_launch(void* const* d_in, const int* in_sizes, int n_in,
                              void* d_out, int out_size, void* d_ws, size_t ws_size,
                              hipStream_t stream) {
    const float* x      = (const float*)d_in[0];
    const float* W_c    = (const float*)d_in[1];
    const float* W_cp   = (const float*)d_in[2];
    const float* W_qc   = (const float*)d_in[3];
    const float* W_qr   = (const float*)d_in[4];
    const float* W_kc   = (const float*)d_in[5];
    const float* W_kr   = (const float*)d_in[6];
    const float* W_v    = (const float*)d_in[7];
    const float* W_o    = (const float*)d_in[8];
    const float* W_idx  = (const float*)d_in[9];
    const float* W_gate = (const float*)d_in[10];
    const float* W_sq   = (const float*)d_in[11];
    const float* W_sk   = (const float*)d_in[12];
    const float* W_sv   = (const float*)d_in[13];
    const float* W_iout = (const float*)d_in[14];
    float* out = (float*)d_out;

    const int ROWS = BB * SS;  // 4096
    float* wsf = (float*)d_ws;
    size_t off = 0;
    auto alloc = [&](size_t n) {
        float* p = wsf + off;
        off += (n + 3) & ~(size_t)3;
        return p;
    };
    auto allocU = [&](size_t n) { return (unsigned short*)alloc((n + 1) / 2); };
    // fp32 buffers
    float* cosT = alloc(SS * 32);
    float* sinT = alloc(SS * 32);
    float* c    = alloc((size_t)ROWS * KVL);
    float* cp   = alloc((size_t)ROWS * QL);       // -> kfull (bf16) after cvt->cpb
    float* krb  = alloc((size_t)ROWS * DR);
    float* idxs = alloc((size_t)ROWS * IHN * IDN);
    float* gate = alloc((size_t)ROWS * IHN);
    float* qcb  = alloc((size_t)ROWS * NH * DK);  // -> attn after fuse_rope_q
    float* qrb  = alloc((size_t)ROWS * NH * DR);
    float* kcb  = alloc((size_t)ROWS * NH * DK);  // -> attnb after fuse_rope_k
    float* vbuf = alloc((size_t)ROWS * NH * DV);  // -> qfull after vtrans
    float* io   = alloc(BB * IHN * 128);
    int* topidx = (int*)alloc(BB * IHN * TOPK);
    // bf16 buffers
    unsigned short* xb    = allocU((size_t)ROWS * HH);  // -> vtb after x-projections
    unsigned short* cb    = allocU((size_t)ROWS * KVL);
    unsigned short* cpb   = allocU((size_t)ROWS * QL);
    unsigned short* WcT   = allocU((size_t)HH * KVL);
    unsigned short* WcpT  = allocU((size_t)HH * QL);
    unsigned short* WqcT  = allocU((size_t)QL * NH * DK);
    unsigned short* WqrT  = allocU((size_t)QL * NH * DR);
    unsigned short* WkcT  = allocU((size_t)KVL * NH * DK);
    unsigned short* WkrT  = allocU((size_t)HH * DR);
    unsigned short* WvT   = allocU((size_t)KVL * NH * DV);
    unsigned short* WidxT = allocU((size_t)HH * IHN * IDN);
    unsigned short* WoT   = allocU((size_t)NH * DV * HH);
    // aliases (stream-ordered reuse; all size-checked: alias <= host buffer)
    unsigned short* kfull = (unsigned short*)cp;    // 24MB in 24MB
    unsigned short* vtb   = (unsigned short*)xb;    // 16MB in 16MB
    unsigned short* qfull = (unsigned short*)vbuf;  // 24MB in 32MB
    unsigned short* attnb = (unsigned short*)kcb;   // 16MB in 32MB
    float* attn           = qcb;                    // 32MB in 32MB
    (void)ws_size; (void)n_in; (void)in_sizes; (void)out_size;

    rope_tables_kernel<<<(SS * 32 + 255) / 256, 256, 0, stream>>>(cosT, sinT);

    // convert x and all GEMM weights (transpose) to bf16
    cvt_bf16<<<(ROWS * HH / 4 + 255) / 256, 256, 0, stream>>>(x, xb, ROWS * HH / 4);
    cvtT_bf16<<<dim3(HH / 32, KVL / 32), 256, 0, stream>>>(W_c, WcT, HH, KVL);
    cvtT_bf16<<<dim3(HH / 32, QL / 32), 256, 0, stream>>>(W_cp, WcpT, HH, QL);
    cvtT_bf16<<<dim3(QL / 32, NH * DK / 32), 256, 0, stream>>>(W_qc, WqcT, QL, NH * DK);
    cvtT_bf16<<<dim3(QL / 32, NH * DR / 32), 256, 0, stream>>>(W_qr, WqrT, QL, NH * DR);
    cvtT_bf16<<<dim3(KVL / 32, NH * DK / 32), 256, 0, stream>>>(W_kc, WkcT, KVL, NH * DK);
    cvtT_bf16<<<dim3(HH / 32, DR / 32), 256, 0, stream>>>(W_kr, WkrT, HH, DR);
    cvtT_bf16<<<dim3(KVL / 32, NH * DV / 32), 256, 0, stream>>>(W_v, WvT, KVL, NH * DV);
    cvtT_bf16<<<dim3(HH / 32, IHN * IDN / 32), 256, 0, stream>>>(W_idx, WidxT, HH, IHN * IDN);
    cvtT_bf16<<<dim3(NH * DV / 32, HH / 32), 256, 0, stream>>>(W_o, WoT, NH * DV, HH);

    // first-level projections (bf16 MFMA); gate exact fp32 (skinny kernel)
    gemm_bf16<<<dim3(KVL / 128, ROWS / 128), 256, 0, stream>>>(xb, WcT, c, ROWS, KVL, HH);
    gemm_bf16<<<dim3(QL / 128, ROWS / 128), 256, 0, stream>>>(xb, WcpT, cp, ROWS, QL, HH);
    gemm_bf16<<<dim3(1, ROWS / 128), 256, 0, stream>>>(xb, WkrT, krb, ROWS, DR, HH);
    gemm_bf16<<<dim3(IHN * IDN / 128, ROWS / 128), 256, 0, stream>>>(xb, WidxT, idxs, ROWS, IHN * IDN, HH);
    gate_gemm<<<ROWS, 256, 0, stream>>>(x, W_gate, gate);

    // second-level projections
    cvt_bf16<<<(ROWS * KVL / 4 + 255) / 256, 256, 0, stream>>>(c, cb, ROWS * KVL / 4);
    cvt_bf16<<<(ROWS * QL / 4 + 255) / 256, 256, 0, stream>>>(cp, cpb, ROWS * QL / 4);  // cp dead after
    gemm_bf16<<<dim3(NH * DK / 128, ROWS / 128), 256, 0, stream>>>(cpb, WqcT, qcb, ROWS, NH * DK, QL);
    gemm_bf16<<<dim3(NH * DR / 128, ROWS / 128), 256, 0, stream>>>(cpb, WqrT, qrb, ROWS, NH * DR, QL);
    gemm_bf16<<<dim3(NH * DK / 128, ROWS / 128), 256, 0, stream>>>(cb, WkcT, kcb, ROWS, NH * DK, KVL);
    gemm_bf16<<<dim3(NH * DV / 128, ROWS / 128), 256, 0, stream>>>(cb, WvT, vbuf, ROWS, NH * DV, KVL);

    // attention operand prep (order matters for aliases):
    // vtrans first (vbuf -> vtb), freeing vbuf for qfull
    vtrans<<<dim3(SS / 32, DV / 32, BB * NH), 256, 0, stream>>>(vbuf, vtb);
    const int fuseBlocks = ROWS * NH * 24 / 256;  // 6144
    fuse_rope_q<<<fuseBlocks, 256, 0, stream>>>(qcb, qrb, cosT, sinT, qfull);  // qcb dead after
    fuse_rope_k<<<fuseBlocks, 256, 0, stream>>>(kcb, krb, cosT, sinT, kfull);  // kcb dead after

    // sparse indexer path (fp32 exact)
    topk_kernel<<<BB * IHN, 256, 0, stream>>>(gate, topidx);
    indexer_kernel<<<BB * IHN, 256, 0, stream>>>(idxs, topidx, W_sq, W_sk, W_sv, W_iout, io);

    // attention (bf16 MFMA) -> attn (reuses qcb region)
    mla_attn_mfma<<<dim3(SS / 64, NH, BB), 256, 0, stream>>>(qfull, kfull, vtb, attn);

    // attn += io broadcast
    add_io<<<(ROWS * NH * DV / 4) / 256, 256, 0, stream>>>(attn, io);

    // output projection (bf16 MFMA)
    cvt_bf16<<<(ROWS * NH * DV / 4 + 255) / 256, 256, 0, stream>>>(attn, attnb, ROWS * NH * DV / 4);
    gemm_bf16<<<dim3(HH / 128, ROWS / 128), 256, 0, stream>>>(attnb, WoT, out, ROWS, HH, HH);
}